// Round 9
// baseline (55.770 us; speedup 1.0000x reference)
//
#include <hip/hip_runtime.h>

typedef __attribute__((ext_vector_type(8))) short short8;
typedef __attribute__((ext_vector_type(4))) float f32x4;

#define CI    128
#define CO_   256
#define HW_   56
#define PLANE 3136
#define NB    16
#define STOT  50176
#define KTOT  1152
#define OUTN  802816   // CO_*PLANE

// ws layout: [0, 12845056) Xt bf16 NHWC ; [12845056, +589824) Wpre bf16 ; then 256B zeros
#define XT_BYTES   12845056ull
#define WP_USHORTS 294912
#define WS_NEED    (12845056ull + 589824ull + 256ull)

__device__ __forceinline__ unsigned short f2bf(float f) {
  unsigned u = __float_as_uint(f);
  u += 0x7FFFu + ((u >> 16) & 1u);   // RNE
  return (unsigned short)(u >> 16);
}

__device__ __forceinline__ void gload16(void* lds, const void* g) {
  __builtin_amdgcn_global_load_lds(
      (const __attribute__((address_space(1))) unsigned int*)g,
      (__attribute__((address_space(3))) unsigned int*)lds, 16, 0, 0);
}

template <int N> __device__ __forceinline__ void vmwait() {
  asm volatile("s_waitcnt vmcnt(%0)" ::"n"(N) : "memory");
}
__device__ __forceinline__ void lgkm0() {
  asm volatile("s_waitcnt lgkmcnt(0)" ::: "memory");
}

// ---------------- fused prep: blocks 0..1599 = prep_x ; 1600..1743 = prep_w ----------------
__global__ __launch_bounds__(256) void prep_fused(const float* __restrict__ X,
                                                  const float* __restrict__ W,
                                                  unsigned short* __restrict__ Xt,
                                                  unsigned short* __restrict__ Wp) {
  const int t = threadIdx.x;
  if (blockIdx.x < 1600) {
    // ---- prep_x: NCHW fp32 -> NHWC bf16 (tiled transpose)
    __shared__ __align__(16) unsigned short tile[32][132];
    const int bx = blockIdx.x;
    const int n   = bx / 100;
    const int rem = bx % 100;
    const int cib = rem / 25;
    const int spb = rem % 25;
    const int sp0 = spb * 128;
    const float* src = X + (size_t)(n * CI + cib * 32) * PLANE;
#pragma unroll
    for (int j = 0; j < 4; ++j) {
      int f = t + 256 * j;
      int ci  = f >> 5;
      int sp4 = (f & 31) * 4;
      if (sp0 + sp4 < PLANE) {
        f32x4 v = *(const f32x4*)(src + (size_t)ci * PLANE + sp0 + sp4);
#pragma unroll
        for (int e = 0; e < 4; ++e) tile[ci][sp4 + e] = f2bf(v[e]);
      }
    }
    __syncthreads();
    unsigned short* dst = Xt + ((size_t)n * PLANE + sp0) * CI + cib * 32;
#pragma unroll
    for (int j = 0; j < 2; ++j) {
      int g = t + 256 * j;
      int sp = g >> 2;
      int q  = g & 3;
      if (sp0 + sp < PLANE) {
        short8 v;
#pragma unroll
        for (int e = 0; e < 8; ++e) v[e] = (short)tile[q * 8 + e][sp];
        *(short8*)(dst + (size_t)sp * CI + q * 8) = v;
      }
    }
  } else {
    // ---- prep_w: OIHW fp32 -> Wpre, R3-proven layout:
    // sub-tile s=(r*4+cb) occupies s*16KB; chunk c (0..1023): co=c>>2,
    // granule holds ci-group kg=(c&3)^((c>>3)&3): ci = cb*32+kg*8+e, tap r.
    const int u = (blockIdx.x - 1600) * 256 + t;   // 0..36863
    const int rcbmt = u >> 9;          // 0..71 = ((r*4+cb)*2+half)
    const int p     = u & 511;
    const int mt  = rcbmt & 1;
    const int rcb = rcbmt >> 1;        // 0..35
    const int cb  = rcb & 3;
    const int r   = rcb >> 2;          // 0..8
    const int col = p >> 2;            // co_local 0..127
    const int kg  = (p & 3) ^ ((col >> 1) & 3);
    const int co  = mt * 128 + col;
    const int ci0 = cb * 32 + kg * 8;
    short8 v;
#pragma unroll
    for (int e = 0; e < 8; ++e)
      v[e] = (short)f2bf(W[(size_t)co * KTOT + (size_t)(ci0 + e) * 9 + r]);
    *(short8*)(Wp + (size_t)u * 8) = v;
    if (u < 16) {
      short8 z = {0, 0, 0, 0, 0, 0, 0, 0};
      *(short8*)(Wp + WP_USHORTS + u * 8) = z;
    }
  }
}

// MFMA cluster: 16 mfma (4m x 2n x 2k) on the given acc rows / bF columns
#define MFMA16(MBASE, NBASE)                                                            \
  __builtin_amdgcn_s_setprio(1);                                                        \
  _Pragma("unroll") for (int k = 0; k < 2; ++k)                                         \
  _Pragma("unroll") for (int m = 0; m < 4; ++m)                                         \
  _Pragma("unroll") for (int n = 0; n < 2; ++n)                                         \
    acc[(MBASE) + m][(NBASE) + n] = __builtin_amdgcn_mfma_f32_16x16x32_bf16(            \
        aF[m][k], bF[(NBASE) + n][k], acc[(MBASE) + m][(NBASE) + n], 0, 0, 0);          \
  __builtin_amdgcn_s_setprio(0);

// ---------------- conv_gemm: 256x256 tile, 8 waves, phased schedule + counted vmcnt ----------
// kt-loop (K=64, 18 iters), 4 phases each. R8 FIX: vmwait+barrier BEFORE phase-0 ds_reads
// (R7 read LDS before staging certification -> race). Counted vmcnt(8), never 0 mid-loop.
// Ring-4 LDS; staging bunched in ph3 (only WAR-safe slot: after ph2's closing barrier,
// every wave's rb0/rb1 reads are complete because its lgkm0 preceded that barrier).
__global__ __launch_bounds__(512, 2) void conv_gemm(const unsigned short* __restrict__ Xt,
                                                    const unsigned short* __restrict__ Wp,
                                                    const float* __restrict__ bias,
                                                    float* __restrict__ out) {
  __shared__ __align__(1024) char smem[131072];  // ring of 4 x (A 16K | B 16K)
  const int t    = threadIdx.x;
  const int lane = t & 63;
  const int wid  = t >> 6;
  const int wm   = wid >> 2, wn = wid & 3;

  // bijective XCD swizzle for 196 blocks (q=24, r=4)
  const int orig = blockIdx.x;
  const int xcd = orig & 7, idx = orig >> 3;
  const int spt = (xcd < 4 ? xcd * 25 : 100 + (xcd - 4) * 24) + idx;   // 0..195

  // --- staging precompute: thread t covers B rows S0 (half 0) and S1 (half 1)
  const int kgB = (t & 3) ^ ((t >> 3) & 3);
  const int S0 = spt * 256 + (t >> 2);
  const int S1 = S0 + 128;
  const int hw0 = S0 % PLANE, h0 = hw0 / HW_, w0 = hw0 - h0 * HW_;
  const int hw1 = S1 % PLANE, h1 = hw1 / HW_, w1 = hw1 - h1 * HW_;
  int vm0 = 0, vm1 = 0;
#pragma unroll
  for (int r = 0; r < 9; ++r) {
    int dh = r / 3 - 1, dw = r % 3 - 1;
    vm0 |= (int)(((unsigned)(h0 + dh) < HW_) & ((unsigned)(w0 + dw) < HW_)) << r;
    vm1 |= (int)(((unsigned)(h1 + dh) < HW_) & ((unsigned)(w1 + dw) < HW_)) << r;
  }
  const char* xb0 = (const char*)Xt + ((size_t)S0 * CI + kgB * 8) * 2;
  const char* xb1 = (const char*)Xt + ((size_t)S1 * CI + kgB * 8) * 2;
  const char* zb  = (const char*)(Wp + WP_USHORTS) + (t & 3) * 16;
  const char* wpA = (const char*)Wp + t * 16;

  // fragment read offsets (64B rows, granule swizzle q^((row>>1)&3), lane-constant)
  const int swz  = ((lane >> 4) ^ ((lane >> 1) & 3)) * 16;
  const int aoff = (wm * 128 + (lane & 15)) * 64 + swz;           // + m*1024
  const int boff = 16384 + (wn * 64 + (lane & 15)) * 64 + swz;    // + n*1024

  f32x4 acc[8][4];
  const f32x4 zf = {0.f, 0.f, 0.f, 0.f};
#pragma unroll
  for (int m = 0; m < 8; ++m)
#pragma unroll
    for (int n = 0; n < 4; ++n) acc[m][n] = zf;

  auto SA = [&](int s1, int j) {
    char* buf = smem + (s1 & 3) * 32768;
    gload16(buf + j * 8192 + wid * 1024, wpA + (size_t)s1 * 16384 + j * 8192);
  };
  auto SB = [&](int s1, int j) {
    char* buf = smem + (s1 & 3) * 32768;
    const int r = s1 >> 2, cb = s1 & 3;
    const int dh = r / 3 - 1, dw = r % 3 - 1;
    const int ro = dh * HW_ + dw;
    const bool v = ((j ? vm1 : vm0) >> r) & 1;
    const char* src = (j ? xb1 : xb0) + ro * 256 + cb * 64;
    gload16(buf + 16384 + j * 8192 + wid * 1024, v ? src : zb);
  };
  auto STAGE = [&](int s1) { SA(s1, 0); SA(s1, 1); SB(s1, 0); SB(s1, 1); };

  // prologue: 4 sub-tiles in flight (fills the ring)
  STAGE(0); STAGE(1); STAGE(2); STAGE(3);

#pragma unroll
  for (int kt = 0; kt < 18; ++kt) {
    const char* rb0 = smem + ((2 * kt) & 3) * 32768;       // k-half 0 (sub 2kt)
    const char* rb1 = smem + ((2 * kt + 1) & 3) * 32768;   // k-half 1 (sub 2kt+1)
    const char* ca0 = rb0 + aoff;
    const char* ca1 = rb1 + aoff;
    const char* cb0 = rb0 + boff;
    const char* cb1 = rb1 + boff;
    short8 aF[4][2], bF[4][2];

    // ===== phase 0: CERTIFY FIRST (R8 fix), then read aF(m0-3)+bF(n0-1); MFMA Q(0,0) =====
    // counted wait: subs 2kt,2kt+1 (staged 2 kt ago) landed; kt-1's 8 stay in flight.
    if (kt <= 16) vmwait<8>();
    else          vmwait<0>();
    __builtin_amdgcn_s_barrier();      // all waves certified -> LDS bufs 2kt,2kt+1 valid
#pragma unroll
    for (int m = 0; m < 4; ++m) {
      aF[m][0] = *(const short8*)(ca0 + m * 1024);
      aF[m][1] = *(const short8*)(ca1 + m * 1024);
    }
#pragma unroll
    for (int n = 0; n < 2; ++n) {
      bF[n][0] = *(const short8*)(cb0 + n * 1024);
      bF[n][1] = *(const short8*)(cb1 + n * 1024);
    }
    lgkm0();
    MFMA16(0, 0)
    __builtin_amdgcn_s_barrier();

    // ===== phase 1: read bF(n2-3); MFMA Q(0,1) =====
#pragma unroll
    for (int n = 0; n < 2; ++n) {
      bF[2 + n][0] = *(const short8*)(cb0 + (2 + n) * 1024);
      bF[2 + n][1] = *(const short8*)(cb1 + (2 + n) * 1024);
    }
    __builtin_amdgcn_s_barrier();
    lgkm0();
    MFMA16(0, 2)
    __builtin_amdgcn_s_barrier();

    // ===== phase 2: read aF(m4-7); MFMA Q(1,1) =====
#pragma unroll
    for (int m = 0; m < 4; ++m) {
      aF[m][0] = *(const short8*)(ca0 + (4 + m) * 1024);
      aF[m][1] = *(const short8*)(ca1 + (4 + m) * 1024);
    }
    __builtin_amdgcn_s_barrier();
    lgkm0();
    MFMA16(4, 2)
    __builtin_amdgcn_s_barrier();

    // ===== phase 3: stage subs 2kt+4, 2kt+5 into the bufs just freed (rb0, rb1);
    //               WAR-safe: all waves' rb0/rb1 reads completed before ph2's closing
    //               barrier (each wave's lgkm0 preceded it). MFMA Q(1,0). =====
    if (kt <= 15) { STAGE(2 * kt + 4); STAGE(2 * kt + 5); }
    __builtin_amdgcn_s_barrier();
    MFMA16(4, 0)
    __builtin_amdgcn_s_barrier();
  }

  // ---- epilogue: D row = co = (lane>>4)*4+reg, col = sp = lane&15
#pragma unroll
  for (int nf = 0; nf < 4; ++nf) {
    int S = spt * 256 + wn * 64 + nf * 16 + (lane & 15);
    int nimg = S / PLANE, hw = S - nimg * PLANE;
    float* ob = out + (size_t)nimg * OUTN + hw;
#pragma unroll
    for (int mf = 0; mf < 8; ++mf) {
      int cob = wm * 128 + mf * 16 + (lane >> 4) * 4;
#pragma unroll
      for (int r2 = 0; r2 < 4; ++r2)
        ob[(size_t)(cob + r2) * PLANE] = acc[mf][nf][r2] + bias[cob + r2];
    }
  }
}

// ---------------- fallback: naive direct conv (only if ws too small) ----------------
__global__ __launch_bounds__(256) void conv_naive(const float* __restrict__ X,
                                                  const float* __restrict__ W,
                                                  const float* __restrict__ bias,
                                                  float* __restrict__ out) {
  int idx = blockIdx.x * 256 + threadIdx.x;
  int hw = idx % PLANE;
  int co = (idx / PLANE) & 255;
  int n  = idx / (PLANE * 256);
  int h = hw / HW_, w = hw - h * HW_;
  float acc = bias[co];
  const float* xp = X + (size_t)n * CI * PLANE;
  const float* wp = W + (size_t)co * KTOT;
  for (int ci = 0; ci < CI; ++ci) {
#pragma unroll
    for (int kh = 0; kh < 3; ++kh) {
      int y = h + kh - 1;
      if ((unsigned)y >= HW_) continue;
#pragma unroll
      for (int kw = 0; kw < 3; ++kw) {
        int x = w + kw - 1;
        if ((unsigned)x >= HW_) continue;
        acc += xp[(size_t)ci * PLANE + y * HW_ + x] * wp[ci * 9 + kh * 3 + kw];
      }
    }
  }
  out[idx] = acc;
}

extern "C" void kernel_launch(void* const* d_in, const int* in_sizes, int n_in,
                              void* d_out, int out_size, void* d_ws, size_t ws_size,
                              hipStream_t stream) {
  (void)in_sizes; (void)n_in; (void)out_size;
  const float* X = (const float*)d_in[0];
  const float* W = (const float*)d_in[1];
  const float* b = (const float*)d_in[2];
  float* out = (float*)d_out;
  if (ws_size >= WS_NEED) {
    unsigned short* Xt = (unsigned short*)d_ws;
    unsigned short* Wp = (unsigned short*)((char*)d_ws + XT_BYTES);
    prep_fused<<<1744, 256, 0, stream>>>(X, W, Xt, Wp);
    conv_gemm<<<196, 512, 0, stream>>>(Xt, Wp, b, out);
  } else {
    conv_naive<<<(NB * CO_ * PLANE + 255) / 256, 256, 0, stream>>>(X, W, b, out);
  }
}

// Round 10
// 52.972 us; speedup vs baseline: 1.0528x; 1.0528x over previous
//
#include <hip/hip_runtime.h>

typedef __attribute__((ext_vector_type(8))) short short8;
typedef __attribute__((ext_vector_type(4))) float f32x4;

#define CI    128
#define CO_   256
#define HW_   56
#define PLANE 3136
#define NB    16
#define STOT  50176
#define KTOT  1152
#define OUTN  802816   // CO_*PLANE

// ws layout: [0, 12845056) Xt bf16 NHWC ; [12845056, +589824) Wpre bf16 ; then 256B zeros
#define XT_BYTES   12845056ull
#define WP_USHORTS 294912
#define WS_NEED    (12845056ull + 589824ull + 256ull)

__device__ __forceinline__ unsigned short f2bf(float f) {
  unsigned u = __float_as_uint(f);
  u += 0x7FFFu + ((u >> 16) & 1u);   // RNE
  return (unsigned short)(u >> 16);
}

__device__ __forceinline__ void gload16(void* lds, const void* g) {
  __builtin_amdgcn_global_load_lds(
      (const __attribute__((address_space(1))) unsigned int*)g,
      (__attribute__((address_space(3))) unsigned int*)lds, 16, 0, 0);
}

// ---------------- fused prep: blocks 0..1599 = prep_x ; 1600..1743 = prep_w ----------------
__global__ __launch_bounds__(256) void prep_fused(const float* __restrict__ X,
                                                  const float* __restrict__ W,
                                                  unsigned short* __restrict__ Xt,
                                                  unsigned short* __restrict__ Wp) {
  const int t = threadIdx.x;
  if (blockIdx.x < 1600) {
    // ---- prep_x: NCHW fp32 -> NHWC bf16 (tiled transpose)
    __shared__ __align__(16) unsigned short tile[32][132];
    const int bx = blockIdx.x;
    const int n   = bx / 100;
    const int rem = bx % 100;
    const int cib = rem / 25;
    const int spb = rem % 25;
    const int sp0 = spb * 128;
    const float* src = X + (size_t)(n * CI + cib * 32) * PLANE;
#pragma unroll
    for (int j = 0; j < 4; ++j) {
      int f = t + 256 * j;
      int ci  = f >> 5;
      int sp4 = (f & 31) * 4;
      if (sp0 + sp4 < PLANE) {
        f32x4 v = *(const f32x4*)(src + (size_t)ci * PLANE + sp0 + sp4);
#pragma unroll
        for (int e = 0; e < 4; ++e) tile[ci][sp4 + e] = f2bf(v[e]);
      }
    }
    __syncthreads();
    unsigned short* dst = Xt + ((size_t)n * PLANE + sp0) * CI + cib * 32;
#pragma unroll
    for (int j = 0; j < 2; ++j) {
      int g = t + 256 * j;
      int sp = g >> 2;
      int q  = g & 3;
      if (sp0 + sp < PLANE) {
        short8 v;
#pragma unroll
        for (int e = 0; e < 8; ++e) v[e] = (short)tile[q * 8 + e][sp];
        *(short8*)(dst + (size_t)sp * CI + q * 8) = v;
      }
    }
  } else {
    // ---- prep_w: OIHW fp32 -> Wpre, R3-proven layout:
    // sub-tile s=(r*4+cb) occupies s*16KB; chunk c (0..1023): co=c>>2,
    // granule holds ci-group kg=(c&3)^((c>>3)&3): ci = cb*32+kg*8+e, tap r.
    const int u = (blockIdx.x - 1600) * 256 + t;   // 0..36863
    const int rcbmt = u >> 9;          // 0..71 = ((r*4+cb)*2+half)
    const int p     = u & 511;
    const int mt  = rcbmt & 1;
    const int rcb = rcbmt >> 1;        // 0..35
    const int cb  = rcb & 3;
    const int r   = rcb >> 2;          // 0..8
    const int col = p >> 2;            // co_local 0..127
    const int kg  = (p & 3) ^ ((col >> 1) & 3);
    const int co  = mt * 128 + col;
    const int ci0 = cb * 32 + kg * 8;
    short8 v;
#pragma unroll
    for (int e = 0; e < 8; ++e)
      v[e] = (short)f2bf(W[(size_t)co * KTOT + (size_t)(ci0 + e) * 9 + r]);
    *(short8*)(Wp + (size_t)u * 8) = v;
    if (u < 16) {
      short8 z = {0, 0, 0, 0, 0, 0, 0, 0};
      *(short8*)(Wp + WP_USHORTS + u * 8) = z;
    }
  }
}

// ---------------- conv_gemm: 256x256, 8 waves, ring-4, REGISTER-PIPELINED frags -------------
// R10: decouple a wave's LDS reads from its MFMAs. Per iter s: wait vmcnt(4)+lgkm(0);
// barrier; STAGE(s+3); ds_read frags(s+1) -> nxt regs; 32 MFMA on cur regs (step s); swap.
// The 12 reads fly WHILE the matrix pipe crunches -> LDS port and MFMA pipe overlap.
// SGB pins [VMEM4][DS12][MFMA32] so the scheduler can't sink the prefetch reads.
__global__ __launch_bounds__(512, 2) void conv_gemm(const unsigned short* __restrict__ Xt,
                                                    const unsigned short* __restrict__ Wp,
                                                    const float* __restrict__ bias,
                                                    float* __restrict__ out) {
  __shared__ __align__(1024) char smem[131072];  // ring of 4 x (A 16K | B 16K)
  const int t    = threadIdx.x;
  const int lane = t & 63;
  const int wid  = t >> 6;
  const int wm   = wid >> 2, wn = wid & 3;

  // bijective XCD swizzle for 196 blocks (q=24, r=4)
  const int orig = blockIdx.x;
  const int xcd = orig & 7, idx = orig >> 3;
  const int spt = (xcd < 4 ? xcd * 25 : 100 + (xcd - 4) * 24) + idx;   // 0..195

  // --- staging precompute: thread t covers B rows S0 (half 0) and S1 (half 1)
  const int kgB = (t & 3) ^ ((t >> 3) & 3);
  const int S0 = spt * 256 + (t >> 2);
  const int S1 = S0 + 128;
  const int hw0 = S0 % PLANE, h0 = hw0 / HW_, w0 = hw0 - h0 * HW_;
  const int hw1 = S1 % PLANE, h1 = hw1 / HW_, w1 = hw1 - h1 * HW_;
  int vm0 = 0, vm1 = 0;
#pragma unroll
  for (int r = 0; r < 9; ++r) {
    int dh = r / 3 - 1, dw = r % 3 - 1;
    vm0 |= (int)(((unsigned)(h0 + dh) < HW_) & ((unsigned)(w0 + dw) < HW_)) << r;
    vm1 |= (int)(((unsigned)(h1 + dh) < HW_) & ((unsigned)(w1 + dw) < HW_)) << r;
  }
  const char* xb0 = (const char*)Xt + ((size_t)S0 * CI + kgB * 8) * 2;
  const char* xb1 = (const char*)Xt + ((size_t)S1 * CI + kgB * 8) * 2;
  const char* zb  = (const char*)(Wp + WP_USHORTS) + (t & 3) * 16;
  const char* wpA = (const char*)Wp + t * 16;

  // fragment read offsets (64B rows, granule swizzle q^((row>>1)&3), lane-constant)
  const int swz  = ((lane >> 4) ^ ((lane >> 1) & 3)) * 16;
  const int aoff = (wm * 128 + (lane & 15)) * 64 + swz;           // + m*1024
  const int boff = 16384 + (wn * 64 + (lane & 15)) * 64 + swz;    // + n*1024

  f32x4 acc[8][4];
  const f32x4 zf = {0.f, 0.f, 0.f, 0.f};
#pragma unroll
  for (int m = 0; m < 8; ++m)
#pragma unroll
    for (int n = 0; n < 4; ++n) acc[m][n] = zf;

  auto SA = [&](int s1, int j) {
    char* buf = smem + (s1 & 3) * 32768;
    gload16(buf + j * 8192 + wid * 1024, wpA + (size_t)s1 * 16384 + j * 8192);
  };
  auto SB = [&](int s1, int j) {
    char* buf = smem + (s1 & 3) * 32768;
    const int r = s1 >> 2, cb = s1 & 3;
    const int dh = r / 3 - 1, dw = r % 3 - 1;
    const int ro = dh * HW_ + dw;
    const bool v = ((j ? vm1 : vm0) >> r) & 1;
    const char* src = (j ? xb1 : xb0) + ro * 256 + cb * 64;
    gload16(buf + 16384 + j * 8192 + wid * 1024, v ? src : zb);
  };
  auto STAGE = [&](int s1) { SA(s1, 0); SA(s1, 1); SB(s1, 0); SB(s1, 1); };

  // prologue: 3 sub-tiles in flight; then certify stage(0) and preload frags(0)
  STAGE(0); STAGE(1); STAGE(2);
  asm volatile("s_waitcnt vmcnt(8)" ::: "memory");
  __builtin_amdgcn_s_barrier();

  short8 curA[8], curB[4], nxtA[8], nxtB[4];
  {
    const char* rb = smem;  // buf 0
#pragma unroll
    for (int m = 0; m < 8; ++m) curA[m] = *(const short8*)(rb + aoff + m * 1024);
#pragma unroll
    for (int n = 0; n < 4; ++n) curB[n] = *(const short8*)(rb + boff + n * 1024);
  }

#pragma unroll
  for (int s = 0; s < 36; ++s) {
    // vmcnt(4): stage(s+1) landed (stage(s+2) stays in flight); lgkm(0): frags(s) done (free).
    if (s <= 33) asm volatile("s_waitcnt vmcnt(4) lgkmcnt(0)" ::: "memory");
    else         asm volatile("s_waitcnt vmcnt(0) lgkmcnt(0)" ::: "memory");
    __builtin_amdgcn_s_barrier();   // all waves certified; buf[(s+3)&3] free (their frag
                                    // reads of it completed before their MFMA(s-1) issued)

    if (s <= 32) STAGE(s + 3);      // 4 VMEM

    if (s <= 34) {                  // prefetch frags(s+1) into nxt regs (12 DS reads)
      const char* rb = smem + ((s + 1) & 3) * 32768;
#pragma unroll
      for (int m = 0; m < 8; ++m) nxtA[m] = *(const short8*)(rb + aoff + m * 1024);
#pragma unroll
      for (int n = 0; n < 4; ++n) nxtB[n] = *(const short8*)(rb + boff + n * 1024);
    }

    __builtin_amdgcn_s_setprio(1);  // 32 MFMA on cur (independent of the in-flight reads)
#pragma unroll
    for (int m = 0; m < 8; ++m)
#pragma unroll
      for (int n = 0; n < 4; ++n)
        acc[m][n] = __builtin_amdgcn_mfma_f32_16x16x32_bf16(curA[m], curB[n], acc[m][n], 0, 0, 0);
    __builtin_amdgcn_s_setprio(0);

    // pin schedule: stage VMEM first, then the 12 prefetch reads, then the MFMA cluster
    __builtin_amdgcn_sched_group_barrier(0x010, 4, 0);   // VMEM (global_load_lds)
    __builtin_amdgcn_sched_group_barrier(0x100, 12, 0);  // DS_READ (frag prefetch)
    __builtin_amdgcn_sched_group_barrier(0x008, 32, 0);  // MFMA

#pragma unroll
    for (int m = 0; m < 8; ++m) curA[m] = nxtA[m];       // static renaming, no scratch
#pragma unroll
    for (int n = 0; n < 4; ++n) curB[n] = nxtB[n];
  }

  // ---- epilogue: D row = co = (lane>>4)*4+reg, col = sp = lane&15
#pragma unroll
  for (int nf = 0; nf < 4; ++nf) {
    int S = spt * 256 + wn * 64 + nf * 16 + (lane & 15);
    int nimg = S / PLANE, hw = S - nimg * PLANE;
    float* ob = out + (size_t)nimg * OUTN + hw;
#pragma unroll
    for (int mf = 0; mf < 8; ++mf) {
      int cob = wm * 128 + mf * 16 + (lane >> 4) * 4;
#pragma unroll
      for (int r2 = 0; r2 < 4; ++r2)
        ob[(size_t)(cob + r2) * PLANE] = acc[mf][nf][r2] + bias[cob + r2];
    }
  }
}

// ---------------- fallback: naive direct conv (only if ws too small) ----------------
__global__ __launch_bounds__(256) void conv_naive(const float* __restrict__ X,
                                                  const float* __restrict__ W,
                                                  const float* __restrict__ bias,
                                                  float* __restrict__ out) {
  int idx = blockIdx.x * 256 + threadIdx.x;
  int hw = idx % PLANE;
  int co = (idx / PLANE) & 255;
  int n  = idx / (PLANE * 256);
  int h = hw / HW_, w = hw - h * HW_;
  float acc = bias[co];
  const float* xp = X + (size_t)n * CI * PLANE;
  const float* wp = W + (size_t)co * KTOT;
  for (int ci = 0; ci < CI; ++ci) {
#pragma unroll
    for (int kh = 0; kh < 3; ++kh) {
      int y = h + kh - 1;
      if ((unsigned)y >= HW_) continue;
#pragma unroll
      for (int kw = 0; kw < 3; ++kw) {
        int x = w + kw - 1;
        if ((unsigned)x >= HW_) continue;
        acc += xp[(size_t)ci * PLANE + y * HW_ + x] * wp[ci * 9 + kh * 3 + kw];
      }
    }
  }
  out[idx] = acc;
}

extern "C" void kernel_launch(void* const* d_in, const int* in_sizes, int n_in,
                              void* d_out, int out_size, void* d_ws, size_t ws_size,
                              hipStream_t stream) {
  (void)in_sizes; (void)n_in; (void)out_size;
  const float* X = (const float*)d_in[0];
  const float* W = (const float*)d_in[1];
  const float* b = (const float*)d_in[2];
  float* out = (float*)d_out;
  if (ws_size >= WS_NEED) {
    unsigned short* Xt = (unsigned short*)d_ws;
    unsigned short* Wp = (unsigned short*)((char*)d_ws + XT_BYTES);
    prep_fused<<<1744, 256, 0, stream>>>(X, W, Xt, Wp);
    conv_gemm<<<196, 512, 0, stream>>>(Xt, Wp, b, out);
  } else {
    conv_naive<<<(NB * CO_ * PLANE + 255) / 256, 256, 0, stream>>>(X, W, b, out);
  }
}

// Round 12
// 50.348 us; speedup vs baseline: 1.1077x; 1.0521x over previous
//
#include <hip/hip_runtime.h>

typedef __attribute__((ext_vector_type(8))) short short8;
typedef __attribute__((ext_vector_type(4))) float f32x4;

#define CI    128
#define CO_   256
#define HW_   56
#define PLANE 3136
#define NB    16
#define STOT  50176
#define KTOT  1152
#define OUTN  802816   // CO_*PLANE
#define PLSZ  3211264ull   // one cb-plane of Xt2: 50176 rows x 64 B

// ws layout: [0, 12845056) Xt2 bf16, 4 planes [cb][S][64B] ; [12845056, +589824) Wpre ; 256B zeros
#define XT_BYTES   12845056ull
#define WP_USHORTS 294912
#define WS_NEED    (12845056ull + 589824ull + 256ull)

__device__ __forceinline__ unsigned short f2bf(float f) {
  unsigned u = __float_as_uint(f);
  u += 0x7FFFu + ((u >> 16) & 1u);   // RNE
  return (unsigned short)(u >> 16);
}

__device__ __forceinline__ void gload16(void* lds, const void* g) {
  __builtin_amdgcn_global_load_lds(
      (const __attribute__((address_space(1))) unsigned int*)g,
      (__attribute__((address_space(3))) unsigned int*)lds, 16, 0, 0);
}

template <int N> __device__ __forceinline__ void vmwait() {
  asm volatile("s_waitcnt vmcnt(%0)" ::"n"(N) : "memory");
}

// ---------------- fused prep: blocks 0..1599 = prep_x ; 1600..1743 = prep_w ----------------
__global__ __launch_bounds__(256) void prep_fused(const float* __restrict__ X,
                                                  const float* __restrict__ W,
                                                  unsigned short* __restrict__ Xt,
                                                  unsigned short* __restrict__ Wp) {
  const int t = threadIdx.x;
  if (blockIdx.x < 1600) {
    // ---- prep_x: NCHW fp32 -> Xt2[cb][S][64B] bf16 (4 contiguous planes)
    __shared__ __align__(16) unsigned short tile[32][132];
    const int bx = blockIdx.x;
    const int n   = bx / 100;
    const int rem = bx % 100;
    const int cib = rem / 25;          // == cb plane
    const int spb = rem % 25;
    const int sp0 = spb * 128;
    const float* src = X + (size_t)(n * CI + cib * 32) * PLANE;
#pragma unroll
    for (int j = 0; j < 4; ++j) {
      int f = t + 256 * j;
      int ci  = f >> 5;
      int sp4 = (f & 31) * 4;
      if (sp0 + sp4 < PLANE) {
        f32x4 v = *(const f32x4*)(src + (size_t)ci * PLANE + sp0 + sp4);
#pragma unroll
        for (int e = 0; e < 4; ++e) tile[ci][sp4 + e] = f2bf(v[e]);
      }
    }
    __syncthreads();
    unsigned short* dstp = Xt + (size_t)cib * (PLSZ / 2) + ((size_t)n * PLANE + sp0) * 32;
#pragma unroll
    for (int j = 0; j < 2; ++j) {
      int g = t + 256 * j;
      int sp = g >> 2;
      int q  = g & 3;                  // 16B granule within the 64B row (plain order)
      if (sp0 + sp < PLANE) {
        short8 v;
#pragma unroll
        for (int e = 0; e < 8; ++e) v[e] = (short)tile[q * 8 + e][sp];
        *(short8*)(dstp + (size_t)sp * 32 + q * 8) = v;
      }
    }
  } else {
    // ---- prep_w: OIHW fp32 -> Wpre (R3-proven layout, unchanged):
    // sub-tile (r,cb,mt) occupies ((r*4+cb)*2+mt)*8KB; chunk p: col=p>>2,
    // granule holds ci-group kg=(p&3)^((col>>1)&3): ci = cb*32+kg*8+e, tap r.
    const int u = (blockIdx.x - 1600) * 256 + t;   // 0..36863
    const int rcbmt = u >> 9;
    const int p     = u & 511;
    const int mt  = rcbmt & 1;
    const int rcb = rcbmt >> 1;
    const int cb  = rcb & 3;
    const int r   = rcb >> 2;
    const int col = p >> 2;
    const int kg  = (p & 3) ^ ((col >> 1) & 3);
    const int co  = mt * 128 + col;
    const int ci0 = cb * 32 + kg * 8;
    short8 v;
#pragma unroll
    for (int e = 0; e < 8; ++e)
      v[e] = (short)f2bf(W[(size_t)co * KTOT + (size_t)(ci0 + e) * 9 + r]);
    *(short8*)(Wp + (size_t)u * 8) = v;
    if (u < 16) {
      short8 z = {0, 0, 0, 0, 0, 0, 0, 0};
      *(short8*)(Wp + WP_USHORTS + u * 8) = z;
    }
  }
}

// ---------------- conv_gemm: R3 structure (best measured) + contiguous-B Xt2 ----------------
// 128x128 tile, 4 waves (2x2, wave 64x64), ring-3 x 16KB, 2 barriers/step, vmcnt(8) counted.
// 784 blocks = 3.06 rounds, 3 blocks/CU (launch_bounds(256,3)) -> cross-block TLP overlap.
// R12 FIX: A-staging dest restored to per-wave slice (buf + wid*1024) -- R11 raced all 4
// waves onto the same KB and left 6KB of the A half unwritten (NaN).
__global__ __launch_bounds__(256, 3) void conv_gemm(const unsigned short* __restrict__ Xt,
                                                    const unsigned short* __restrict__ Wp,
                                                    const float* __restrict__ bias,
                                                    float* __restrict__ out) {
  __shared__ __align__(1024) char smem[49152];  // ring of 3 x (A 8KB | B 8KB)
  const int t    = threadIdx.x;
  const int lane = t & 63;
  const int wid  = t >> 6;
  const int wm   = wid >> 1, wn = wid & 1;

  int bx = blockIdx.x;
  bx = (bx & 7) * 98 + (bx >> 3);     // XCD swizzle, bijective (784 = 8*98)
  const int mt  = bx & 1;
  const int spt = bx >> 1;            // 0..391

  // --- B staging: gload g=wid*2+j covers rows g*16..+15; lane -> row g*16+(lane>>2),
  //     LDS granule lane&3 (linear dest); source granule pre-swizzled kgB.
  const int kgB = (lane & 3) ^ ((lane >> 3) & 3);   // = dest granule ^ ((row>>1)&3)
  const int S0 = spt * 128 + wid * 32 + (lane >> 2);      // j=0 row
  const int S1 = S0 + 16;                                  // j=1 row
  const int hw0 = S0 % PLANE, h0 = hw0 / HW_, w0 = hw0 - h0 * HW_;
  const int hw1 = S1 % PLANE, h1 = hw1 / HW_, w1 = hw1 - h1 * HW_;
  int vm0 = 0, vm1 = 0;
#pragma unroll
  for (int r = 0; r < 9; ++r) {
    int dh = r / 3 - 1, dw = r % 3 - 1;
    vm0 |= (int)(((unsigned)(h0 + dh) < HW_) & ((unsigned)(w0 + dw) < HW_)) << r;
    vm1 |= (int)(((unsigned)(h1 + dh) < HW_) & ((unsigned)(w1 + dw) < HW_)) << r;
  }
  const char* xb0 = (const char*)Xt + (size_t)S0 * 64 + kgB * 16;
  const char* xb1 = (const char*)Xt + (size_t)S1 * 64 + kgB * 16;
  const char* zb  = (const char*)(Wp + WP_USHORTS) + (lane & 3) * 16;
  const char* wpA = (const char*)Wp + mt * 8192 + t * 16;

  // fragment read offsets (64B rows, granule swizzle kg^((row>>1)&3), lane-constant)
  const int swz  = ((lane >> 4) ^ ((lane >> 1) & 3)) * 16;
  const int aoff = (wm * 64 + (lane & 15)) * 64 + swz;          // + m*1024
  const int boff = 8192 + (wn * 64 + (lane & 15)) * 64 + swz;   // + n*1024

  f32x4 acc[4][4];
  const f32x4 zf = {0.f, 0.f, 0.f, 0.f};
#pragma unroll
  for (int m = 0; m < 4; ++m)
#pragma unroll
    for (int n = 0; n < 4; ++n) acc[m][n] = zf;

  auto STAGE = [&](int s1) {
    char* buf = smem + (s1 % 3) * 16384;
    const int r = s1 >> 2, cb = s1 & 3;
    const int dh = r / 3 - 1, dw = r % 3 - 1;
    const long  ro = (long)(dh * HW_ + dw) * 64 + (long)cb * PLSZ;  // byte shift into plane cb
    const char* as = wpA + r * 65536 + cb * 16384;
    char* abuf = buf + wid * 1024;             // per-wave A slice (R12 fix)
    gload16(abuf, as);                         // A rows: wave quarter of 0..63
    gload16(abuf + 4096, as + 4096);           // A rows: wave quarter of 64..127
    const bool v0 = (vm0 >> r) & 1;
    const bool v1 = (vm1 >> r) & 1;
    gload16(buf + 8192 + wid * 2048,        v0 ? xb0 + ro : zb);   // B rows g=wid*2
    gload16(buf + 8192 + wid * 2048 + 1024, v1 ? xb1 + ro : zb);   // B rows g=wid*2+1
  };

  // prologue: 3 sub-tiles in flight (12 gloads)
  STAGE(0); STAGE(1); STAGE(2);

#pragma unroll
  for (int s = 0; s < 36; ++s) {
    // counted wait: stage s's 4 loads (oldest) landed; 8 stay in flight. Never 0 mid-loop.
    if (s <= 33)      vmwait<8>();
    else if (s == 34) vmwait<4>();
    else              vmwait<0>();
    __builtin_amdgcn_s_barrier();      // stage-s data visible to all waves

    const char* rb = smem + (s % 3) * 16384;
    short8 a[4], b[4];
#pragma unroll
    for (int m = 0; m < 4; ++m) a[m] = *(const short8*)(rb + aoff + m * 1024);
#pragma unroll
    for (int n = 0; n < 4; ++n) b[n] = *(const short8*)(rb + boff + n * 1024);

    __builtin_amdgcn_s_setprio(1);
#pragma unroll
    for (int m = 0; m < 4; ++m)
#pragma unroll
      for (int n = 0; n < 4; ++n)
        acc[m][n] = __builtin_amdgcn_mfma_f32_16x16x32_bf16(a[m], b[n], acc[m][n], 0, 0, 0);
    __builtin_amdgcn_s_setprio(0);

    if (s < 33) {
      __builtin_amdgcn_s_barrier();    // all waves done reading buf[s%3] (WAR)
      STAGE(s + 3);
    }
  }

  // ---- epilogue: D row = co = (lane>>4)*4+reg, col = sp = lane&15
#pragma unroll
  for (int nf = 0; nf < 4; ++nf) {
    int S = spt * 128 + wn * 64 + nf * 16 + (lane & 15);
    int nimg = S / PLANE, hw = S - nimg * PLANE;
    float* ob = out + (size_t)nimg * OUTN + hw;
#pragma unroll
    for (int mf = 0; mf < 4; ++mf) {
      int cob = mt * 128 + wm * 64 + mf * 16 + (lane >> 4) * 4;
#pragma unroll
      for (int r2 = 0; r2 < 4; ++r2)
        ob[(size_t)(cob + r2) * PLANE] = acc[mf][nf][r2] + bias[cob + r2];
    }
  }
}

// ---------------- fallback: naive direct conv (only if ws too small) ----------------
__global__ __launch_bounds__(256) void conv_naive(const float* __restrict__ X,
                                                  const float* __restrict__ W,
                                                  const float* __restrict__ bias,
                                                  float* __restrict__ out) {
  int idx = blockIdx.x * 256 + threadIdx.x;
  int hw = idx % PLANE;
  int co = (idx / PLANE) & 255;
  int n  = idx / (PLANE * 256);
  int h = hw / HW_, w = hw - h * HW_;
  float acc = bias[co];
  const float* xp = X + (size_t)n * CI * PLANE;
  const float* wp = W + (size_t)co * KTOT;
  for (int ci = 0; ci < CI; ++ci) {
#pragma unroll
    for (int kh = 0; kh < 3; ++kh) {
      int y = h + kh - 1;
      if ((unsigned)y >= HW_) continue;
#pragma unroll
      for (int kw = 0; kw < 3; ++kw) {
        int x = w + kw - 1;
        if ((unsigned)x >= HW_) continue;
        acc += xp[(size_t)ci * PLANE + y * HW_ + x] * wp[ci * 9 + kh * 3 + kw];
      }
    }
  }
  out[idx] = acc;
}

extern "C" void kernel_launch(void* const* d_in, const int* in_sizes, int n_in,
                              void* d_out, int out_size, void* d_ws, size_t ws_size,
                              hipStream_t stream) {
  (void)in_sizes; (void)n_in; (void)out_size;
  const float* X = (const float*)d_in[0];
  const float* W = (const float*)d_in[1];
  const float* b = (const float*)d_in[2];
  float* out = (float*)d_out;
  if (ws_size >= WS_NEED) {
    unsigned short* Xt = (unsigned short*)d_ws;
    unsigned short* Wp = (unsigned short*)((char*)d_ws + XT_BYTES);
    prep_fused<<<1744, 256, 0, stream>>>(X, W, Xt, Wp);
    conv_gemm<<<784, 256, 0, stream>>>(Xt, Wp, b, out);
  } else {
    conv_naive<<<(NB * CO_ * PLANE + 255) / 256, 256, 0, stream>>>(X, W, b, out);
  }
}